// Round 1
// baseline (45.039 us; speedup 1.0000x reference)
//
#include <hip/hip_runtime.h>

// out = w <= -0.5 ? -0.125 : (w > 0.5 ? 0.125 : 0)
// (derived from: clip to [-1,1], nearest of levels [-8,-4,-2,-1,0,1,2,4,8]
//  with first-min tie-break -> only {-1,0,1} reachable; then /8 scaling;
//  STE forward output == w_q/8. Tie at -0.5 -> -1 (index 3 first),
//  tie at +0.5 -> 0 (index 4 first).)

__device__ __forceinline__ float quant1(float w) {
    return (w <= -0.5f) ? -0.125f : ((w > 0.5f) ? 0.125f : 0.0f);
}

__global__ void hcq_kernel_v4(const float4* __restrict__ in,
                              float4* __restrict__ out, int n4) {
    int idx = blockIdx.x * blockDim.x + threadIdx.x;
    int stride = gridDim.x * blockDim.x;
    for (int i = idx; i < n4; i += stride) {
        float4 v = in[i];
        float4 r;
        r.x = quant1(v.x);
        r.y = quant1(v.y);
        r.z = quant1(v.z);
        r.w = quant1(v.w);
        out[i] = r;
    }
}

__global__ void hcq_kernel_tail(const float* __restrict__ in,
                                float* __restrict__ out, int n0, int n) {
    int i = n0 + blockIdx.x * blockDim.x + threadIdx.x;
    if (i < n) out[i] = quant1(in[i]);
}

extern "C" void kernel_launch(void* const* d_in, const int* in_sizes, int n_in,
                              void* d_out, int out_size, void* d_ws, size_t ws_size,
                              hipStream_t stream) {
    const float* w = (const float*)d_in[0];
    float* out = (float*)d_out;
    int n = in_sizes[0];

    int n4 = n / 4;
    if (n4 > 0) {
        int block = 256;
        long long want = ((long long)n4 + block - 1) / block;
        int grid = (int)(want < 2048 ? want : 2048);
        hcq_kernel_v4<<<grid, block, 0, stream>>>((const float4*)w, (float4*)out, n4);
    }
    int rem = n - n4 * 4;
    if (rem > 0) {
        hcq_kernel_tail<<<1, 64, 0, stream>>>(w, out, n4 * 4, n);
    }
}